// Round 1
// baseline (974.619 us; speedup 1.0000x reference)
//
#include <hip/hip_runtime.h>
#include <math.h>

#define HDIM 70
#define HPAD 72
#define GATES 280
#define NG 288        // gates padded to 18*16
#define TLEN 512
#define BATCH 128
#define CDIM 1104
#define KW 1152       // K padded to 18*64
#define ROWS 65536    // BATCH*TLEN

// ws layout (float offsets)
#define OFF_WRN   0          // 1104*70 fp32 -> 77280 (round 77312)
#define OFF_BIAS  77312      // 280 fp32 (round 320)
#define OFF_WCT   77632      // 288*1152 bf16 = 165888 floats
#define OFF_XG    243520     // 65536*280 bf16 = 9175040 floats
#define OFF_HOUT  9418560    // 65536*72 fp32 = 4718592
#define OFF_EN    14137152   // 65536 fp32

typedef short short8 __attribute__((ext_vector_type(8)));
typedef float f32x4 __attribute__((ext_vector_type(4)));

__device__ __forceinline__ unsigned short f2bf(float f) {
    unsigned int u = __float_as_uint(f);
    u = (u + 0x7fffu + ((u >> 16) & 1u)) >> 16;
    return (unsigned short)u;
}
__device__ __forceinline__ float bf2f(unsigned short s) {
    return __uint_as_float(((unsigned int)s) << 16);
}

// ---------------- K1: row renorm of embed_w ----------------
__global__ __launch_bounds__(64) void k_renorm(const float* __restrict__ w,
                                               float* __restrict__ wrn) {
    const int row = blockIdx.x;
    const int lane = threadIdx.x;
    const float* wr = w + row * HDIM;
    float v0 = wr[lane];
    float v1 = (lane < 6) ? wr[64 + lane] : 0.0f;
    float ss = v0 * v0 + v1 * v1;
    #pragma unroll
    for (int off = 32; off > 0; off >>= 1) ss += __shfl_down(ss, off);
    float tot = __shfl(ss, 0);
    float n = sqrtf(tot);
    float scale = (n > 1.0f) ? 1.0f / (n + 1e-7f) : 1.0f;
    wrn[row * HDIM + lane] = v0 * scale;
    if (lane < 6) wrn[row * HDIM + 64 + lane] = v1 * scale;
}

// ---------------- K2: WcT[n][k] = sum_h w_ih[n][h]*wrn[k][h], bf16, padded ----------------
__global__ __launch_bounds__(256) void k_prep(const float* __restrict__ wrn,
                                              const float* __restrict__ w_ih,
                                              const float* __restrict__ b_ih,
                                              const float* __restrict__ b_hh,
                                              unsigned short* __restrict__ wcT,
                                              float* __restrict__ bias) {
    const int n = blockIdx.x;      // 0..287
    const int tid = threadIdx.x;
    float wr[HDIM];
    if (n < GATES) {
        #pragma unroll
        for (int h = 0; h < HDIM; ++h) wr[h] = w_ih[n * HDIM + h];
        if (tid == 0) bias[n] = b_ih[n] + b_hh[n];
    } else {
        #pragma unroll
        for (int h = 0; h < HDIM; ++h) wr[h] = 0.0f;
    }
    for (int c = tid; c < KW; c += 256) {
        float a = 0.0f;
        if (n < GATES && c < CDIM) {
            const float* wc = wrn + c * HDIM;
            #pragma unroll
            for (int h = 0; h < HDIM; ++h) a += wr[h] * wc[h];
        }
        wcT[(size_t)n * KW + c] = f2bf(a);
    }
}

// ---------------- K3: xg = x @ Wc + bias  (bf16 MFMA, M=65536,N=288,K=1152) ----------------
// block: 256 thr (4 waves, 2x2 wave grid), tile M=128 x N=288, K-chunks of 64.
__global__ __launch_bounds__(256, 2) void k_xg_gemm(const float* __restrict__ x,
                                                    const unsigned short* __restrict__ wcT,
                                                    const float* __restrict__ bias,
                                                    unsigned short* __restrict__ xg) {
    __shared__ __align__(16) unsigned short A_lds[128 * 72];  // [row][k] stride 72
    __shared__ __align__(16) unsigned short B_lds[NG * 72];   // [n][k]   stride 72
    const int tid = threadIdx.x;
    const int lane = tid & 63;
    const int w = tid >> 6;
    const int mh = (w >> 1) * 64;     // wave M-half: 0 or 64
    const int nh = (w & 1) * 144;     // wave N-half: 0 or 144 (9 n-tiles)
    const int l15 = lane & 15;
    const int q = lane >> 4;
    const size_t rbase = (size_t)blockIdx.x * 128;

    f32x4 acc[4][9];
    #pragma unroll
    for (int mt = 0; mt < 4; ++mt)
        #pragma unroll
        for (int nt = 0; nt < 9; ++nt) acc[mt][nt] = (f32x4){0.f, 0.f, 0.f, 0.f};

    const int r_st = tid >> 1;
    const int kh_st = (tid & 1) * 32;

    for (int kc = 0; kc < 18; ++kc) {
        const int k0 = kc * 64;
        // stage A: 128 rows x 64 k fp32 -> bf16
        {
            const float* xr = x + (rbase + r_st) * (size_t)CDIM + k0 + kh_st;
            unsigned short* dst = &A_lds[r_st * 72 + kh_st];
            #pragma unroll
            for (int qq = 0; qq < 8; ++qq) {
                const int kk = k0 + kh_st + qq * 4;
                float4 v = make_float4(0.f, 0.f, 0.f, 0.f);
                if (kk < CDIM) v = *(const float4*)(xr + qq * 4);
                unsigned int lo = (unsigned int)f2bf(v.x) | ((unsigned int)f2bf(v.y) << 16);
                unsigned int hi = (unsigned int)f2bf(v.z) | ((unsigned int)f2bf(v.w) << 16);
                uint2 pv; pv.x = lo; pv.y = hi;
                *(uint2*)&dst[qq * 4] = pv;
            }
        }
        // stage B: 288 n x 64 k bf16 (already padded with zeros)
        {
            #pragma unroll
            for (int p = 0; p < 9; ++p) {
                const int cid = tid + p * 256;
                const int n = cid >> 3;
                const int ko = (cid & 7) * 8;
                uint4 v = *(const uint4*)(wcT + (size_t)n * KW + k0 + ko);
                *(uint4*)&B_lds[n * 72 + ko] = v;
            }
        }
        __syncthreads();
        #pragma unroll
        for (int ks = 0; ks < 2; ++ks) {
            short8 a[4];
            short8 bfr[9];
            #pragma unroll
            for (int mt = 0; mt < 4; ++mt)
                a[mt] = *(const short8*)&A_lds[(mh + mt * 16 + l15) * 72 + ks * 32 + q * 8];
            #pragma unroll
            for (int nt = 0; nt < 9; ++nt)
                bfr[nt] = *(const short8*)&B_lds[(nh + nt * 16 + l15) * 72 + ks * 32 + q * 8];
            #pragma unroll
            for (int mt = 0; mt < 4; ++mt)
                #pragma unroll
                for (int nt = 0; nt < 9; ++nt)
                    acc[mt][nt] = __builtin_amdgcn_mfma_f32_16x16x32_bf16(a[mt], bfr[nt], acc[mt][nt], 0, 0, 0);
        }
        __syncthreads();
    }
    // epilogue: + bias, store bf16. D: m=(q*4+r), n=l15 within tile.
    #pragma unroll
    for (int nt = 0; nt < 9; ++nt) {
        const int n_g = nh + nt * 16 + l15;
        if (n_g >= GATES) continue;
        const float bv = bias[n_g];
        #pragma unroll
        for (int mt = 0; mt < 4; ++mt) {
            #pragma unroll
            for (int r = 0; r < 4; ++r) {
                const size_t row = rbase + mh + mt * 16 + q * 4 + r;
                xg[row * GATES + n_g] = f2bf(acc[mt][nt][r] + bv);
            }
        }
    }
}

// ---------------- K4: LSTM scan, gate-fused lanes + K-split butterfly ----------------
// thread = (j, kq): lane = jj + 16*kq, j = wave*16 + jj (j in 0..79, valid < 70).
// Each thread: partial dots for gates {i,f,g,o} of its j over k in [kq*20, kq*20+20).
// shfl_xor(16)+shfl_xor(32) completes the 4 dots in-register -> c/h update is lane-local.
// ONE barrier per step, double-buffered h_lds. No gates_lds.
__device__ __forceinline__ float tanh_fast(float v) {
    v = fminf(fmaxf(v, -20.0f), 20.0f);
    float E = __expf(2.0f * v);
    return (E - 1.0f) / (E + 1.0f);
}
__device__ __forceinline__ float sigmoid_fast(float v) {
    return 1.0f / (1.0f + __expf(-v));
}

#define PF 8
#define KCH 20        // k-chunk per lane-group
#define HP2 80        // h padded to 4*KCH

__global__ __launch_bounds__(320) void k_lstm(const unsigned short* __restrict__ xg,
                                              const float* __restrict__ w_hh,
                                              float* __restrict__ hout) {
    __shared__ __align__(16) float h_lds[2][HP2];
    const int tid = threadIdx.x;
    const int b = blockIdx.x;
    const int wv = tid >> 6;
    const int l = tid & 63;
    const int jj = l & 15;
    const int kq = l >> 4;
    const int j = wv * 16 + jj;          // 0..79
    const bool jvalid = (j < HDIM);
    const bool lead = (kq == 0) && jvalid;

    // per-thread weights: 4 gates x 20 k (zero-padded)
    float wr0[KCH], wr1[KCH], wr2[KCH], wr3[KCH];
    #pragma unroll
    for (int kk = 0; kk < KCH; ++kk) {
        const int k = kq * KCH + kk;
        const bool kv = jvalid && (k < HDIM);
        wr0[kk] = kv ? w_hh[(0 * HDIM + j) * HDIM + k] : 0.0f;
        wr1[kk] = kv ? w_hh[(1 * HDIM + j) * HDIM + k] : 0.0f;
        wr2[kk] = kv ? w_hh[(2 * HDIM + j) * HDIM + k] : 0.0f;
        wr3[kk] = kv ? w_hh[(3 * HDIM + j) * HDIM + k] : 0.0f;
    }

    if (tid < 2 * HP2) ((float*)h_lds)[tid] = 0.0f;
    float c_reg = 0.0f;

    // xg prefetch (lead lanes only): 4 gate values per step, PF steps ahead
    const unsigned short* xp = xg + (size_t)b * TLEN * GATES;
    float xb0[PF], xb1[PF], xb2[PF], xb3[PF];
    if (lead) {
        #pragma unroll
        for (int i = 0; i < PF; ++i) {
            xb0[i] = bf2f(xp[i * GATES + 0 * HDIM + j]);
            xb1[i] = bf2f(xp[i * GATES + 1 * HDIM + j]);
            xb2[i] = bf2f(xp[i * GATES + 2 * HDIM + j]);
            xb3[i] = bf2f(xp[i * GATES + 3 * HDIM + j]);
        }
    }
    __syncthreads();

    int cur = 0;
    #pragma unroll 8
    for (int t = 0; t < TLEN; ++t) {
        const int slot = t & (PF - 1);
        // read own k-quarter of h
        f32x4 hv[5];
        const f32x4* hp4 = (const f32x4*)&h_lds[cur][kq * KCH];
        #pragma unroll
        for (int qi = 0; qi < 5; ++qi) hv[qi] = hp4[qi];

        float a0 = 0.f, a1 = 0.f, a2 = 0.f, a3 = 0.f;
        #pragma unroll
        for (int qi = 0; qi < 5; ++qi) {
            #pragma unroll
            for (int e = 0; e < 4; ++e) {
                const float hvv = hv[qi][e];
                const int kk = qi * 4 + e;
                a0 = fmaf(hvv, wr0[kk], a0);
                a1 = fmaf(hvv, wr1[kk], a1);
                a2 = fmaf(hvv, wr2[kk], a2);
                a3 = fmaf(hvv, wr3[kk], a3);
            }
        }
        // butterfly reduce over kq (lane bits 4,5)
        a0 += __shfl_xor(a0, 16); a1 += __shfl_xor(a1, 16);
        a2 += __shfl_xor(a2, 16); a3 += __shfl_xor(a3, 16);
        a0 += __shfl_xor(a0, 32); a1 += __shfl_xor(a1, 32);
        a2 += __shfl_xor(a2, 32); a3 += __shfl_xor(a3, 32);

        if (lead) {
            const float xi = xb0[slot], xf = xb1[slot], xg_ = xb2[slot], xo = xb3[slot];
            const int tp = (t + PF) & (TLEN - 1);
            xb0[slot] = bf2f(xp[tp * GATES + 0 * HDIM + j]);
            xb1[slot] = bf2f(xp[tp * GATES + 1 * HDIM + j]);
            xb2[slot] = bf2f(xp[tp * GATES + 2 * HDIM + j]);
            xb3[slot] = bf2f(xp[tp * GATES + 3 * HDIM + j]);
            const float iv = sigmoid_fast(a0 + xi);
            const float fv = sigmoid_fast(a1 + xf);
            const float gv = tanh_fast(a2 + xg_);
            const float ov = sigmoid_fast(a3 + xo);
            c_reg = fv * c_reg + iv * gv;
            const float hn = ov * tanh_fast(c_reg);
            h_lds[cur ^ 1][j] = hn;
            hout[((size_t)b * TLEN + t) * HPAD + j] = hn;
        }
        __syncthreads();
        cur ^= 1;
    }
}

// ---------------- K5a: attention energy ----------------
__global__ __launch_bounds__(256) void k_energy(const float* __restrict__ hout,
                                                const float* __restrict__ w1,
                                                const float* __restrict__ b1,
                                                const float* __restrict__ w2,
                                                const float* __restrict__ b2,
                                                float* __restrict__ energy) {
    const int lane = threadIdx.x & 63;
    const int wid = blockIdx.x * 4 + (threadIdx.x >> 6);
    float w1r[HPAD];
    #pragma unroll
    for (int c = 0; c < HDIM; ++c) w1r[c] = w1[lane * HDIM + c];
    w1r[70] = w1r[71] = 0.0f;
    const float b1v = b1[lane];
    const float w2v = w2[lane];
    const float b2v = b2[0];
    for (int row = wid; row < ROWS; row += 4096) {
        const float4* rp = (const float4*)(hout + (size_t)row * HPAD);
        float a0 = 0.f, a1 = 0.f, a2 = 0.f, a3 = 0.f;
        #pragma unroll
        for (int jj = 0; jj < 18; ++jj) {
            float4 v = rp[jj];
            a0 += v.x * w1r[4 * jj];
            a1 += v.y * w1r[4 * jj + 1];
            a2 += v.z * w1r[4 * jj + 2];
            a3 += v.w * w1r[4 * jj + 3];
        }
        float hid = fmaxf((a0 + a1) + (a2 + a3) + b1v, 0.0f) * w2v;
        #pragma unroll
        for (int off = 32; off > 0; off >>= 1) hid += __shfl_down(hid, off);
        if (lane == 0) energy[row] = hid + b2v;
    }
}

// ---------------- K5b: softmax-pool + FC + softmax ----------------
__global__ __launch_bounds__(128) void k_pool(const float* __restrict__ hout,
                                              const float* __restrict__ energy,
                                              const float* __restrict__ fc_w,
                                              const float* __restrict__ fc_b,
                                              float* __restrict__ outp) {
    __shared__ float red[128];
    __shared__ float wexp[TLEN];
    __shared__ float pooledL[HDIM];
    const int tid = threadIdx.x;
    const int b = blockIdx.x;
    float v[4];
    #pragma unroll
    for (int k = 0; k < 4; ++k) v[k] = energy[b * TLEN + tid + 128 * k];
    float m = fmaxf(fmaxf(v[0], v[1]), fmaxf(v[2], v[3]));
    red[tid] = m; __syncthreads();
    for (int s = 64; s > 0; s >>= 1) {
        if (tid < s) red[tid] = fmaxf(red[tid], red[tid + s]);
        __syncthreads();
    }
    const float M = red[0]; __syncthreads();
    float s4 = 0.f;
    #pragma unroll
    for (int k = 0; k < 4; ++k) {
        float ex = __expf(v[k] - M);
        wexp[tid + 128 * k] = ex;
        s4 += ex;
    }
    red[tid] = s4; __syncthreads();
    for (int s = 64; s > 0; s >>= 1) {
        if (tid < s) red[tid] += red[tid + s];
        __syncthreads();
    }
    const float rinv = 1.0f / red[0];
    if (tid < HDIM) {
        float a0 = 0.f, a1 = 0.f, a2 = 0.f, a3 = 0.f;
        const float* hp = hout + (size_t)b * TLEN * HPAD + tid;
        for (int s = 0; s < TLEN; s += 4) {
            a0 += wexp[s]     * hp[(size_t)(s)     * HPAD];
            a1 += wexp[s + 1] * hp[(size_t)(s + 1) * HPAD];
            a2 += wexp[s + 2] * hp[(size_t)(s + 2) * HPAD];
            a3 += wexp[s + 3] * hp[(size_t)(s + 3) * HPAD];
        }
        pooledL[tid] = ((a0 + a1) + (a2 + a3)) * rinv;
    }
    __syncthreads();
    if (tid == 0) {
        float l[3];
        #pragma unroll
        for (int i = 0; i < 3; ++i) {
            float a = fc_b[i];
            for (int h = 0; h < HDIM; ++h) a += fc_w[i * HDIM + h] * pooledL[h];
            l[i] = a;
        }
        float m3 = fmaxf(l[0], fmaxf(l[1], l[2]));
        float e0 = __expf(l[0] - m3), e1 = __expf(l[1] - m3), e2 = __expf(l[2] - m3);
        float rs = 1.0f / (e0 + e1 + e2);
        outp[b * 3 + 0] = e0 * rs;
        outp[b * 3 + 1] = e1 * rs;
        outp[b * 3 + 2] = e2 * rs;
    }
}

extern "C" void kernel_launch(void* const* d_in, const int* in_sizes, int n_in,
                              void* d_out, int out_size, void* d_ws, size_t ws_size,
                              hipStream_t stream) {
    const float* x       = (const float*)d_in[0];
    const float* embed_w = (const float*)d_in[1];
    const float* w_ih    = (const float*)d_in[2];
    const float* w_hh    = (const float*)d_in[3];
    const float* b_ih    = (const float*)d_in[4];
    const float* b_hh    = (const float*)d_in[5];
    const float* aw1     = (const float*)d_in[6];
    const float* ab1     = (const float*)d_in[7];
    const float* aw2     = (const float*)d_in[8];
    const float* ab2     = (const float*)d_in[9];
    const float* fc_w    = (const float*)d_in[10];
    const float* fc_b    = (const float*)d_in[11];
    float* outp = (float*)d_out;
    float* ws = (float*)d_ws;

    float* wrn  = ws + OFF_WRN;
    float* bias = ws + OFF_BIAS;
    unsigned short* wcT = (unsigned short*)(ws + OFF_WCT);
    unsigned short* xgp = (unsigned short*)(ws + OFF_XG);
    float* ho = ws + OFF_HOUT;
    float* en = ws + OFF_EN;

    k_renorm<<<CDIM, 64, 0, stream>>>(embed_w, wrn);
    k_prep<<<NG, 256, 0, stream>>>(wrn, w_ih, b_ih, b_hh, wcT, bias);
    k_xg_gemm<<<512, 256, 0, stream>>>(x, wcT, bias, xgp);
    k_lstm<<<BATCH, 320, 0, stream>>>(xgp, w_hh, ho);
    k_energy<<<1024, 256, 0, stream>>>(ho, aw1, ab1, aw2, ab2, en);
    k_pool<<<BATCH, 128, 0, stream>>>(ho, en, fc_w, fc_b, outp);
}

// Round 2
// 841.638 us; speedup vs baseline: 1.1580x; 1.1580x over previous
//
#include <hip/hip_runtime.h>
#include <math.h>

#define HDIM 70
#define HPAD 72
#define GATES 280
#define NG 288        // gates padded to 18*16
#define TLEN 512
#define BATCH 128
#define CDIM 1104
#define KW 1152       // K padded to 18*64
#define ROWS 65536    // BATCH*TLEN

// ws layout (float offsets)
#define OFF_WRN   0          // 1104*70 fp32 -> 77280 (round 77312)
#define OFF_BIAS  77312      // 280 fp32 (round 320)
#define OFF_WCT   77632      // 288*1152 bf16 = 165888 floats
#define OFF_XG    243520     // 65536*280 bf16 = 9175040 floats
#define OFF_HOUT  9418560    // 65536*72 fp32 = 4718592
#define OFF_EN    14137152   // 65536 fp32

typedef short short8 __attribute__((ext_vector_type(8)));
typedef float f32x4 __attribute__((ext_vector_type(4)));

__device__ __forceinline__ unsigned short f2bf(float f) {
    unsigned int u = __float_as_uint(f);
    u = (u + 0x7fffu + ((u >> 16) & 1u)) >> 16;
    return (unsigned short)u;
}
__device__ __forceinline__ float bf2f(unsigned short s) {
    return __uint_as_float(((unsigned int)s) << 16);
}

// ---------------- K1: row renorm of embed_w ----------------
__global__ __launch_bounds__(64) void k_renorm(const float* __restrict__ w,
                                               float* __restrict__ wrn) {
    const int row = blockIdx.x;
    const int lane = threadIdx.x;
    const float* wr = w + row * HDIM;
    float v0 = wr[lane];
    float v1 = (lane < 6) ? wr[64 + lane] : 0.0f;
    float ss = v0 * v0 + v1 * v1;
    #pragma unroll
    for (int off = 32; off > 0; off >>= 1) ss += __shfl_down(ss, off);
    float tot = __shfl(ss, 0);
    float n = sqrtf(tot);
    float scale = (n > 1.0f) ? 1.0f / (n + 1e-7f) : 1.0f;
    wrn[row * HDIM + lane] = v0 * scale;
    if (lane < 6) wrn[row * HDIM + 64 + lane] = v1 * scale;
}

// ---------------- K2: WcT[n][k] = sum_h w_ih[n][h]*wrn[k][h], bf16, padded ----------------
__global__ __launch_bounds__(256) void k_prep(const float* __restrict__ wrn,
                                              const float* __restrict__ w_ih,
                                              const float* __restrict__ b_ih,
                                              const float* __restrict__ b_hh,
                                              unsigned short* __restrict__ wcT,
                                              float* __restrict__ bias) {
    const int n = blockIdx.x;      // 0..287
    const int tid = threadIdx.x;
    float wr[HDIM];
    if (n < GATES) {
        #pragma unroll
        for (int h = 0; h < HDIM; ++h) wr[h] = w_ih[n * HDIM + h];
        if (tid == 0) bias[n] = b_ih[n] + b_hh[n];
    } else {
        #pragma unroll
        for (int h = 0; h < HDIM; ++h) wr[h] = 0.0f;
    }
    for (int c = tid; c < KW; c += 256) {
        float a = 0.0f;
        if (n < GATES && c < CDIM) {
            const float* wc = wrn + c * HDIM;
            #pragma unroll
            for (int h = 0; h < HDIM; ++h) a += wr[h] * wc[h];
        }
        wcT[(size_t)n * KW + c] = f2bf(a);
    }
}

// ---------------- K3: xg = x @ Wc + bias  (bf16 MFMA, M=65536,N=288,K=1152) ----------------
// block: 256 thr (4 waves, 2x2 wave grid), tile M=128 x N=288, K-chunks of 64.
__global__ __launch_bounds__(256, 2) void k_xg_gemm(const float* __restrict__ x,
                                                    const unsigned short* __restrict__ wcT,
                                                    const float* __restrict__ bias,
                                                    unsigned short* __restrict__ xg) {
    __shared__ __align__(16) unsigned short A_lds[128 * 72];  // [row][k] stride 72
    __shared__ __align__(16) unsigned short B_lds[NG * 72];   // [n][k]   stride 72
    const int tid = threadIdx.x;
    const int lane = tid & 63;
    const int w = tid >> 6;
    const int mh = (w >> 1) * 64;     // wave M-half: 0 or 64
    const int nh = (w & 1) * 144;     // wave N-half: 0 or 144 (9 n-tiles)
    const int l15 = lane & 15;
    const int q = lane >> 4;
    const size_t rbase = (size_t)blockIdx.x * 128;

    f32x4 acc[4][9];
    #pragma unroll
    for (int mt = 0; mt < 4; ++mt)
        #pragma unroll
        for (int nt = 0; nt < 9; ++nt) acc[mt][nt] = (f32x4){0.f, 0.f, 0.f, 0.f};

    const int r_st = tid >> 1;
    const int kh_st = (tid & 1) * 32;

    for (int kc = 0; kc < 18; ++kc) {
        const int k0 = kc * 64;
        // stage A: 128 rows x 64 k fp32 -> bf16
        {
            const float* xr = x + (rbase + r_st) * (size_t)CDIM + k0 + kh_st;
            unsigned short* dst = &A_lds[r_st * 72 + kh_st];
            #pragma unroll
            for (int qq = 0; qq < 8; ++qq) {
                const int kk = k0 + kh_st + qq * 4;
                float4 v = make_float4(0.f, 0.f, 0.f, 0.f);
                if (kk < CDIM) v = *(const float4*)(xr + qq * 4);
                unsigned int lo = (unsigned int)f2bf(v.x) | ((unsigned int)f2bf(v.y) << 16);
                unsigned int hi = (unsigned int)f2bf(v.z) | ((unsigned int)f2bf(v.w) << 16);
                uint2 pv; pv.x = lo; pv.y = hi;
                *(uint2*)&dst[qq * 4] = pv;
            }
        }
        // stage B: 288 n x 64 k bf16 (already padded with zeros)
        {
            #pragma unroll
            for (int p = 0; p < 9; ++p) {
                const int cid = tid + p * 256;
                const int n = cid >> 3;
                const int ko = (cid & 7) * 8;
                uint4 v = *(const uint4*)(wcT + (size_t)n * KW + k0 + ko);
                *(uint4*)&B_lds[n * 72 + ko] = v;
            }
        }
        __syncthreads();
        #pragma unroll
        for (int ks = 0; ks < 2; ++ks) {
            short8 a[4];
            short8 bfr[9];
            #pragma unroll
            for (int mt = 0; mt < 4; ++mt)
                a[mt] = *(const short8*)&A_lds[(mh + mt * 16 + l15) * 72 + ks * 32 + q * 8];
            #pragma unroll
            for (int nt = 0; nt < 9; ++nt)
                bfr[nt] = *(const short8*)&B_lds[(nh + nt * 16 + l15) * 72 + ks * 32 + q * 8];
            #pragma unroll
            for (int mt = 0; mt < 4; ++mt)
                #pragma unroll
                for (int nt = 0; nt < 9; ++nt)
                    acc[mt][nt] = __builtin_amdgcn_mfma_f32_16x16x32_bf16(a[mt], bfr[nt], acc[mt][nt], 0, 0, 0);
        }
        __syncthreads();
    }
    // epilogue: + bias, store bf16. D: m=(q*4+r), n=l15 within tile.
    #pragma unroll
    for (int nt = 0; nt < 9; ++nt) {
        const int n_g = nh + nt * 16 + l15;
        if (n_g >= GATES) continue;
        const float bv = bias[n_g];
        #pragma unroll
        for (int mt = 0; mt < 4; ++mt) {
            #pragma unroll
            for (int r = 0; r < 4; ++r) {
                const size_t row = rbase + mh + mt * 16 + q * 4 + r;
                xg[row * GATES + n_g] = f2bf(acc[mt][nt][r] + bv);
            }
        }
    }
}

// ---------------- K4: LSTM scan — round-0 structure + DPP quad gate exchange ----------------
// thread = (j, g): lane l -> jm = l>>2, g = l&3; j = wave*16 + jm (valid j < 70).
// Each thread: full 70-dot for gate g of hidden j (h via broadcast LDS reads, as round 0),
// activation in parallel across all 280 gate threads (as round 0), then 4 quad-broadcast
// DPP movs put {i,f,g,o} of j in every quad lane -> c/h update lane-local (redundant x4).
// No gates_lds, ONE barrier per step, double-buffered h_lds.
__device__ __forceinline__ float tanh_fast(float v) {
    v = fminf(fmaxf(v, -20.0f), 20.0f);
    float E = __expf(2.0f * v);
    return (E - 1.0f) / (E + 1.0f);
}
__device__ __forceinline__ float sigmoid_fast(float v) {
    return 1.0f / (1.0f + __expf(-v));
}

#define PF 8
__global__ __launch_bounds__(320) void k_lstm(const unsigned short* __restrict__ xg,
                                              const float* __restrict__ w_hh,
                                              float* __restrict__ hout) {
    __shared__ __align__(16) float h_lds[2][HPAD];
    const int tid = threadIdx.x;
    const int b = blockIdx.x;
    const int w = tid >> 6;
    const int l = tid & 63;
    const int jm = l >> 2;
    const int g = l & 3;              // 0:i 1:f 2:g(tanh) 3:o  (PyTorch order)
    const int j = w * 16 + jm;        // 0..79, valid < 70
    const bool jv = (j < HDIM);

    // weight row for (gate g, hidden j): w_hh row = g*70 + j
    float whh[HPAD];
    if (jv) {
        const float* wr = w_hh + (size_t)(g * HDIM + j) * HDIM;
        #pragma unroll
        for (int k = 0; k < HDIM; ++k) whh[k] = wr[k];
        whh[70] = whh[71] = 0.0f;
    } else {
        #pragma unroll
        for (int k = 0; k < HPAD; ++k) whh[k] = 0.0f;
    }
    if (tid < 2 * HPAD) ((float*)h_lds)[tid] = 0.0f;
    float c_reg = 0.0f;

    // xg ring prefetch: one bf16 per thread per step, PF steps ahead
    const int goff = jv ? (g * HDIM + j) : 0;
    const unsigned short* xp = xg + (size_t)b * TLEN * GATES + goff;
    float xbuf[PF];
    #pragma unroll
    for (int i = 0; i < PF; ++i) xbuf[i] = bf2f(xp[i * GATES]);
    __syncthreads();

    int cur = 0;
    #pragma unroll 8
    for (int t = 0; t < TLEN; ++t) {
        const int slot = t & (PF - 1);
        const float xcur = xbuf[slot];
        xbuf[slot] = bf2f(xp[((t + PF) & (TLEN - 1)) * GATES]);  // prefetch 8 ahead

        // broadcast read of h (uniform-address ds_read_b128, proven cheap in round 0)
        const f32x4* hp4 = (const f32x4*)h_lds[cur];
        float a0 = 0.f, a1 = 0.f, a2 = 0.f, a3 = 0.f;
        #pragma unroll
        for (int kk = 0; kk < 18; ++kk) {
            f32x4 hv = hp4[kk];
            a0 = fmaf(hv.x, whh[4 * kk + 0], a0);
            a1 = fmaf(hv.y, whh[4 * kk + 1], a1);
            a2 = fmaf(hv.z, whh[4 * kk + 2], a2);
            a3 = fmaf(hv.w, whh[4 * kk + 3], a3);
        }
        const float acc = xcur + ((a0 + a1) + (a2 + a3));
        // activation in parallel across all gate threads
        const float act = (g == 2) ? tanh_fast(acc) : sigmoid_fast(acc);

        // quad broadcasts: every lane of the quad gets i,f,g,o (VALU DPP, not LDS pipe)
        const int ai = __float_as_int(act);
        const float i_v = __int_as_float(__builtin_amdgcn_mov_dpp(ai, 0x00, 0xF, 0xF, true));
        const float f_v = __int_as_float(__builtin_amdgcn_mov_dpp(ai, 0x55, 0xF, 0xF, true));
        const float t_v = __int_as_float(__builtin_amdgcn_mov_dpp(ai, 0xAA, 0xF, 0xF, true));
        const float o_v = __int_as_float(__builtin_amdgcn_mov_dpp(ai, 0xFF, 0xF, 0xF, true));

        c_reg = f_v * c_reg + i_v * t_v;           // redundant x4 within quad (consistent)
        const float hn = o_v * tanh_fast(c_reg);
        if (g == 0 && jv) {
            h_lds[cur ^ 1][j] = hn;
            hout[((size_t)b * TLEN + t) * HPAD + j] = hn;
        }
        __syncthreads();
        cur ^= 1;
    }
}

// ---------------- K5a: attention energy ----------------
__global__ __launch_bounds__(256) void k_energy(const float* __restrict__ hout,
                                                const float* __restrict__ w1,
                                                const float* __restrict__ b1,
                                                const float* __restrict__ w2,
                                                const float* __restrict__ b2,
                                                float* __restrict__ energy) {
    const int lane = threadIdx.x & 63;
    const int wid = blockIdx.x * 4 + (threadIdx.x >> 6);
    float w1r[HPAD];
    #pragma unroll
    for (int c = 0; c < HDIM; ++c) w1r[c] = w1[lane * HDIM + c];
    w1r[70] = w1r[71] = 0.0f;
    const float b1v = b1[lane];
    const float w2v = w2[lane];
    const float b2v = b2[0];
    for (int row = wid; row < ROWS; row += 4096) {
        const float4* rp = (const float4*)(hout + (size_t)row * HPAD);
        float a0 = 0.f, a1 = 0.f, a2 = 0.f, a3 = 0.f;
        #pragma unroll
        for (int jj = 0; jj < 18; ++jj) {
            float4 v = rp[jj];
            a0 += v.x * w1r[4 * jj];
            a1 += v.y * w1r[4 * jj + 1];
            a2 += v.z * w1r[4 * jj + 2];
            a3 += v.w * w1r[4 * jj + 3];
        }
        float hid = fmaxf((a0 + a1) + (a2 + a3) + b1v, 0.0f) * w2v;
        #pragma unroll
        for (int off = 32; off > 0; off >>= 1) hid += __shfl_down(hid, off);
        if (lane == 0) energy[row] = hid + b2v;
    }
}

// ---------------- K5b: softmax-pool + FC + softmax ----------------
__global__ __launch_bounds__(128) void k_pool(const float* __restrict__ hout,
                                              const float* __restrict__ energy,
                                              const float* __restrict__ fc_w,
                                              const float* __restrict__ fc_b,
                                              float* __restrict__ outp) {
    __shared__ float red[128];
    __shared__ float wexp[TLEN];
    __shared__ float pooledL[HDIM];
    const int tid = threadIdx.x;
    const int b = blockIdx.x;
    float v[4];
    #pragma unroll
    for (int k = 0; k < 4; ++k) v[k] = energy[b * TLEN + tid + 128 * k];
    float m = fmaxf(fmaxf(v[0], v[1]), fmaxf(v[2], v[3]));
    red[tid] = m; __syncthreads();
    for (int s = 64; s > 0; s >>= 1) {
        if (tid < s) red[tid] = fmaxf(red[tid], red[tid + s]);
        __syncthreads();
    }
    const float M = red[0]; __syncthreads();
    float s4 = 0.f;
    #pragma unroll
    for (int k = 0; k < 4; ++k) {
        float ex = __expf(v[k] - M);
        wexp[tid + 128 * k] = ex;
        s4 += ex;
    }
    red[tid] = s4; __syncthreads();
    for (int s = 64; s > 0; s >>= 1) {
        if (tid < s) red[tid] += red[tid + s];
        __syncthreads();
    }
    const float rinv = 1.0f / red[0];
    if (tid < HDIM) {
        float a0 = 0.f, a1 = 0.f, a2 = 0.f, a3 = 0.f;
        const float* hp = hout + (size_t)b * TLEN * HPAD + tid;
        for (int s = 0; s < TLEN; s += 4) {
            a0 += wexp[s]     * hp[(size_t)(s)     * HPAD];
            a1 += wexp[s + 1] * hp[(size_t)(s + 1) * HPAD];
            a2 += wexp[s + 2] * hp[(size_t)(s + 2) * HPAD];
            a3 += wexp[s + 3] * hp[(size_t)(s + 3) * HPAD];
        }
        pooledL[tid] = ((a0 + a1) + (a2 + a3)) * rinv;
    }
    __syncthreads();
    if (tid == 0) {
        float l[3];
        #pragma unroll
        for (int i = 0; i < 3; ++i) {
            float a = fc_b[i];
            for (int h = 0; h < HDIM; ++h) a += fc_w[i * HDIM + h] * pooledL[h];
            l[i] = a;
        }
        float m3 = fmaxf(l[0], fmaxf(l[1], l[2]));
        float e0 = __expf(l[0] - m3), e1 = __expf(l[1] - m3), e2 = __expf(l[2] - m3);
        float rs = 1.0f / (e0 + e1 + e2);
        outp[b * 3 + 0] = e0 * rs;
        outp[b * 3 + 1] = e1 * rs;
        outp[b * 3 + 2] = e2 * rs;
    }
}

extern "C" void kernel_launch(void* const* d_in, const int* in_sizes, int n_in,
                              void* d_out, int out_size, void* d_ws, size_t ws_size,
                              hipStream_t stream) {
    const float* x       = (const float*)d_in[0];
    const float* embed_w = (const float*)d_in[1];
    const float* w_ih    = (const float*)d_in[2];
    const float* w_hh    = (const float*)d_in[3];
    const float* b_ih    = (const float*)d_in[4];
    const float* b_hh    = (const float*)d_in[5];
    const float* aw1     = (const float*)d_in[6];
    const float* ab1     = (const float*)d_in[7];
    const float* aw2     = (const float*)d_in[8];
    const float* ab2     = (const float*)d_in[9];
    const float* fc_w    = (const float*)d_in[10];
    const float* fc_b    = (const float*)d_in[11];
    float* outp = (float*)d_out;
    float* ws = (float*)d_ws;

    float* wrn  = ws + OFF_WRN;
    float* bias = ws + OFF_BIAS;
    unsigned short* wcT = (unsigned short*)(ws + OFF_WCT);
    unsigned short* xgp = (unsigned short*)(ws + OFF_XG);
    float* ho = ws + OFF_HOUT;
    float* en = ws + OFF_EN;

    k_renorm<<<CDIM, 64, 0, stream>>>(embed_w, wrn);
    k_prep<<<NG, 256, 0, stream>>>(wrn, w_ih, b_ih, b_hh, wcT, bias);
    k_xg_gemm<<<512, 256, 0, stream>>>(x, wcT, bias, xgp);
    k_lstm<<<BATCH, 320, 0, stream>>>(xgp, w_hh, ho);
    k_energy<<<1024, 256, 0, stream>>>(ho, aw1, ab1, aw2, ab2, en);
    k_pool<<<BATCH, 128, 0, stream>>>(ho, en, fc_w, fc_b, outp);
}

// Round 4
// 824.291 us; speedup vs baseline: 1.1824x; 1.0210x over previous
//
#include <hip/hip_runtime.h>
#include <math.h>

#define HDIM 70
#define HPAD 72
#define GATES 280
#define NG 288        // gates padded to 18*16
#define TLEN 512
#define BATCH 128
#define CDIM 1104
#define KW 1152       // K padded to 18*64
#define ROWS 65536    // BATCH*TLEN

// ws layout (float offsets)
#define OFF_WRN   0          // 1104*70 fp32 -> 77280 (round 77312)
#define OFF_BIAS  77312      // 280 fp32 (round 320)
#define OFF_WCT   77632      // 288*1152 bf16 = 165888 floats
#define OFF_XG    243520     // 65536*280 bf16 = 9175040 floats
#define OFF_HOUT  9418560    // 65536*72 fp32 = 4718592
#define OFF_EN    14137152   // 65536 fp32

typedef short short8 __attribute__((ext_vector_type(8)));
typedef float f32x4 __attribute__((ext_vector_type(4)));

__device__ __forceinline__ unsigned short f2bf(float f) {
    unsigned int u = __float_as_uint(f);
    u = (u + 0x7fffu + ((u >> 16) & 1u)) >> 16;
    return (unsigned short)u;
}
__device__ __forceinline__ float bf2f(unsigned short s) {
    return __uint_as_float(((unsigned int)s) << 16);
}

// ---------------- K1: row renorm of embed_w ----------------
__global__ __launch_bounds__(64) void k_renorm(const float* __restrict__ w,
                                               float* __restrict__ wrn) {
    const int row = blockIdx.x;
    const int lane = threadIdx.x;
    const float* wr = w + row * HDIM;
    float v0 = wr[lane];
    float v1 = (lane < 6) ? wr[64 + lane] : 0.0f;
    float ss = v0 * v0 + v1 * v1;
    #pragma unroll
    for (int off = 32; off > 0; off >>= 1) ss += __shfl_down(ss, off);
    float tot = __shfl(ss, 0);
    float n = sqrtf(tot);
    float scale = (n > 1.0f) ? 1.0f / (n + 1e-7f) : 1.0f;
    wrn[row * HDIM + lane] = v0 * scale;
    if (lane < 6) wrn[row * HDIM + 64 + lane] = v1 * scale;
}

// ---------------- K2: WcT[n][k] = sum_h w_ih[n][h]*wrn[k][h], bf16, padded ----------------
__global__ __launch_bounds__(256) void k_prep(const float* __restrict__ wrn,
                                              const float* __restrict__ w_ih,
                                              const float* __restrict__ b_ih,
                                              const float* __restrict__ b_hh,
                                              unsigned short* __restrict__ wcT,
                                              float* __restrict__ bias) {
    const int n = blockIdx.x;      // 0..287
    const int tid = threadIdx.x;
    float wr[HDIM];
    if (n < GATES) {
        #pragma unroll
        for (int h = 0; h < HDIM; ++h) wr[h] = w_ih[n * HDIM + h];
        if (tid == 0) bias[n] = b_ih[n] + b_hh[n];
    } else {
        #pragma unroll
        for (int h = 0; h < HDIM; ++h) wr[h] = 0.0f;
    }
    for (int c = tid; c < KW; c += 256) {
        float a = 0.0f;
        if (n < GATES && c < CDIM) {
            const float* wc = wrn + c * HDIM;
            #pragma unroll
            for (int h = 0; h < HDIM; ++h) a += wr[h] * wc[h];
        }
        wcT[(size_t)n * KW + c] = f2bf(a);
    }
}

// ---------------- K3: xg = x @ Wc + bias  (bf16 MFMA, M=65536,N=288,K=1152) ----------------
// block: 256 thr (4 waves, 2x2 wave grid), tile M=128 x N=288, K-chunks of 64.
__global__ __launch_bounds__(256, 2) void k_xg_gemm(const float* __restrict__ x,
                                                    const unsigned short* __restrict__ wcT,
                                                    const float* __restrict__ bias,
                                                    unsigned short* __restrict__ xg) {
    __shared__ __align__(16) unsigned short A_lds[128 * 72];  // [row][k] stride 72
    __shared__ __align__(16) unsigned short B_lds[NG * 72];   // [n][k]   stride 72
    const int tid = threadIdx.x;
    const int lane = tid & 63;
    const int w = tid >> 6;
    const int mh = (w >> 1) * 64;     // wave M-half: 0 or 64
    const int nh = (w & 1) * 144;     // wave N-half: 0 or 144 (9 n-tiles)
    const int l15 = lane & 15;
    const int q = lane >> 4;
    const size_t rbase = (size_t)blockIdx.x * 128;

    f32x4 acc[4][9];
    #pragma unroll
    for (int mt = 0; mt < 4; ++mt)
        #pragma unroll
        for (int nt = 0; nt < 9; ++nt) acc[mt][nt] = (f32x4){0.f, 0.f, 0.f, 0.f};

    const int r_st = tid >> 1;
    const int kh_st = (tid & 1) * 32;

    for (int kc = 0; kc < 18; ++kc) {
        const int k0 = kc * 64;
        // stage A: 128 rows x 64 k fp32 -> bf16
        {
            const float* xr = x + (rbase + r_st) * (size_t)CDIM + k0 + kh_st;
            unsigned short* dst = &A_lds[r_st * 72 + kh_st];
            #pragma unroll
            for (int qq = 0; qq < 8; ++qq) {
                const int kk = k0 + kh_st + qq * 4;
                float4 v = make_float4(0.f, 0.f, 0.f, 0.f);
                if (kk < CDIM) v = *(const float4*)(xr + qq * 4);
                unsigned int lo = (unsigned int)f2bf(v.x) | ((unsigned int)f2bf(v.y) << 16);
                unsigned int hi = (unsigned int)f2bf(v.z) | ((unsigned int)f2bf(v.w) << 16);
                uint2 pv; pv.x = lo; pv.y = hi;
                *(uint2*)&dst[qq * 4] = pv;
            }
        }
        // stage B: 288 n x 64 k bf16 (already padded with zeros)
        {
            #pragma unroll
            for (int p = 0; p < 9; ++p) {
                const int cid = tid + p * 256;
                const int n = cid >> 3;
                const int ko = (cid & 7) * 8;
                uint4 v = *(const uint4*)(wcT + (size_t)n * KW + k0 + ko);
                *(uint4*)&B_lds[n * 72 + ko] = v;
            }
        }
        __syncthreads();
        #pragma unroll
        for (int ks = 0; ks < 2; ++ks) {
            short8 a[4];
            short8 bfr[9];
            #pragma unroll
            for (int mt = 0; mt < 4; ++mt)
                a[mt] = *(const short8*)&A_lds[(mh + mt * 16 + l15) * 72 + ks * 32 + q * 8];
            #pragma unroll
            for (int nt = 0; nt < 9; ++nt)
                bfr[nt] = *(const short8*)&B_lds[(nh + nt * 16 + l15) * 72 + ks * 32 + q * 8];
            #pragma unroll
            for (int mt = 0; mt < 4; ++mt)
                #pragma unroll
                for (int nt = 0; nt < 9; ++nt)
                    acc[mt][nt] = __builtin_amdgcn_mfma_f32_16x16x32_bf16(a[mt], bfr[nt], acc[mt][nt], 0, 0, 0);
        }
        __syncthreads();
    }
    // epilogue: + bias, store bf16. D: m=(q*4+r), n=l15 within tile.
    #pragma unroll
    for (int nt = 0; nt < 9; ++nt) {
        const int n_g = nh + nt * 16 + l15;
        if (n_g >= GATES) continue;
        const float bv = bias[n_g];
        #pragma unroll
        for (int mt = 0; mt < 4; ++mt) {
            #pragma unroll
            for (int r = 0; r < 4; ++r) {
                const size_t row = rbase + mh + mt * 16 + q * 4 + r;
                xg[row * GATES + n_g] = f2bf(acc[mt][nt][r] + bv);
            }
        }
    }
}

// ---------------- K4: LSTM scan — K-split x2, 3 waves, raw barrier (no vmcnt drain) ----------------
// thread = (j, kh): tid = j*2 + kh, j in 0..95 (valid < 70), kh = K-half.
// Each thread: partials for ALL 4 gates of its j over h[kh*36 .. kh*36+36) -> 9 ds_read_b128.
// Quad DPP swap-add (0xB1) over kh completes the 4 sums in-register on both lanes.
// Lane kh activates gates {2kh, 2kh+1}; tanh(x) = 2*sigmoid(2x)-1 keeps code uniform.
// 4 quad DPP broadcasts give every lane i,f,g,o -> lane-local c/h (redundant x2).
// In-loop barrier: s_waitcnt lgkmcnt(0) + raw s_barrier -> vmcnt NOT drained, so the
// 8-deep xg prefetch and the hout stores stay in flight across steps.
__device__ __forceinline__ float sigmoid_fast(float v) {
    return 1.0f / (1.0f + __expf(-v));
}

#define DPPF(x, ctrl) __int_as_float(__builtin_amdgcn_mov_dpp(__float_as_int(x), (ctrl), 0xF, 0xF, true))

#define PF 8
__global__ __launch_bounds__(192) void k_lstm(const unsigned short* __restrict__ xg,
                                              const float* __restrict__ w_hh,
                                              float* __restrict__ hout) {
    __shared__ __align__(16) float h_lds[2][HPAD];
    const int tid = threadIdx.x;
    const int b = blockIdx.x;
    const int jl = tid >> 1;      // 0..95, valid < 70
    const int kh = tid & 1;
    const bool jv = (jl < HDIM);

    // act0: even lane = sigmoid(i) -> (s,m,b)=(1,1,0); odd lane = tanh(g)=2*sig(2x)-1 -> (2,2,-1)
    const float s0 = kh ? 2.0f : 1.0f;
    const float m0 = kh ? 2.0f : 1.0f;
    const float c0 = kh ? -1.0f : 0.0f;

    // weights: 4 gates x 36 k (zero-padded); w_hh[(g*70+j)*70 + k]
    float wr0[36], wr1[36], wr2[36], wr3[36];
    #pragma unroll
    for (int kk = 0; kk < 36; ++kk) {
        const int k = kh * 36 + kk;
        const bool kv = jv && (k < HDIM);
        const size_t base = (size_t)jl * HDIM + k;
        wr0[kk] = kv ? w_hh[base] : 0.0f;
        wr1[kk] = kv ? w_hh[1 * HDIM * HDIM + base] : 0.0f;
        wr2[kk] = kv ? w_hh[2 * HDIM * HDIM + base] : 0.0f;
        wr3[kk] = kv ? w_hh[3 * HDIM * HDIM + base] : 0.0f;
    }
    if (tid < 2 * HPAD) ((float*)h_lds)[tid] = 0.0f;
    float c_reg = 0.0f;

    // xg ring prefetch: 2 bf16 per thread per step (this lane's 2 gates), PF ahead.
    // even lane: gates i(j), f(70+j); odd lane: gates g(140+j), o(210+j)
    const int jc = jv ? jl : 0;
    const unsigned short* xpA = xg + (size_t)b * TLEN * GATES + kh * 140 + jc;
    const unsigned short* xpB = xpA + 70;
    float xbA[PF], xbB[PF];
    #pragma unroll
    for (int i = 0; i < PF; ++i) {
        xbA[i] = bf2f(xpA[i * GATES]);
        xbB[i] = bf2f(xpB[i * GATES]);
    }
    __syncthreads();

    #pragma unroll 8
    for (int t = 0; t < TLEN; ++t) {
        const int slot = t & (PF - 1);
        const int cu = t & 1;
        const float uA = xbA[slot];
        const float uB = xbB[slot];
        const int tp = (t + PF) & (TLEN - 1);
        xbA[slot] = bf2f(xpA[tp * GATES]);
        xbB[slot] = bf2f(xpB[tp * GATES]);

        // own K-half of h: 9 x ds_read_b128 (2 distinct addrs per read -> bank-clean)
        const f32x4* hp4 = (const f32x4*)&h_lds[cu][kh * 36];
        float a0 = 0.f, a1 = 0.f, a2 = 0.f, a3 = 0.f;
        #pragma unroll
        for (int qi = 0; qi < 9; ++qi) {
            f32x4 hv = hp4[qi];
            #pragma unroll
            for (int e = 0; e < 4; ++e) {
                const float hvv = hv[e];
                const int kk = qi * 4 + e;
                a0 = fmaf(hvv, wr0[kk], a0);
                a1 = fmaf(hvv, wr1[kk], a1);
                a2 = fmaf(hvv, wr2[kk], a2);
                a3 = fmaf(hvv, wr3[kk], a3);
            }
        }
        // complete the 4 dots across kh (quad swap 0xB1 = [1,0,3,2])
        a0 += DPPF(a0, 0xB1); a1 += DPPF(a1, 0xB1);
        a2 += DPPF(a2, 0xB1); a3 += DPPF(a3, 0xB1);

        // this lane's 2 gates: even -> (i,f)=(a0,a1); odd -> (g,o)=(a2,a3)
        const float t0 = (kh ? a2 : a0) + uA;
        const float t1 = (kh ? a3 : a1) + uB;
        const float act0 = fmaf(m0, sigmoid_fast(s0 * t0), c0);  // sig(i) or tanh(g)
        const float act1 = sigmoid_fast(t1);                     // sig(f) or sig(o)

        // quad broadcasts: i,f from even lane; g,o from odd lane
        const float i_v = DPPF(act0, 0xA0);
        const float f_v = DPPF(act1, 0xA0);
        const float g_v = DPPF(act0, 0xF5);
        const float o_v = DPPF(act1, 0xF5);

        c_reg = fmaf(f_v, c_reg, i_v * g_v);
        const float hn = o_v * fmaf(2.0f, sigmoid_fast(2.0f * c_reg), -1.0f);
        if (kh == 0 && jv) {
            h_lds[cu ^ 1][jl] = hn;
            hout[((size_t)b * TLEN + t) * HPAD + jl] = hn;
        }
        // LDS handoff only: drain lgkm, NOT vmcnt (keeps prefetch/stores in flight)
        asm volatile("s_waitcnt lgkmcnt(0)" ::: "memory");
        __builtin_amdgcn_s_barrier();
        __builtin_amdgcn_sched_barrier(0);
    }
}

// ---------------- K5a: attention energy ----------------
__global__ __launch_bounds__(256) void k_energy(const float* __restrict__ hout,
                                                const float* __restrict__ w1,
                                                const float* __restrict__ b1,
                                                const float* __restrict__ w2,
                                                const float* __restrict__ b2,
                                                float* __restrict__ energy) {
    const int lane = threadIdx.x & 63;
    const int wid = blockIdx.x * 4 + (threadIdx.x >> 6);
    float w1r[HPAD];
    #pragma unroll
    for (int c = 0; c < HDIM; ++c) w1r[c] = w1[lane * HDIM + c];
    w1r[70] = w1r[71] = 0.0f;
    const float b1v = b1[lane];
    const float w2v = w2[lane];
    const float b2v = b2[0];
    for (int row = wid; row < ROWS; row += 4096) {
        const float4* rp = (const float4*)(hout + (size_t)row * HPAD);
        float a0 = 0.f, a1 = 0.f, a2 = 0.f, a3 = 0.f;
        #pragma unroll
        for (int jj = 0; jj < 18; ++jj) {
            float4 v = rp[jj];
            a0 += v.x * w1r[4 * jj];
            a1 += v.y * w1r[4 * jj + 1];
            a2 += v.z * w1r[4 * jj + 2];
            a3 += v.w * w1r[4 * jj + 3];
        }
        float hid = fmaxf((a0 + a1) + (a2 + a3) + b1v, 0.0f) * w2v;
        #pragma unroll
        for (int off = 32; off > 0; off >>= 1) hid += __shfl_down(hid, off);
        if (lane == 0) energy[row] = hid + b2v;
    }
}

// ---------------- K5b: softmax-pool + FC + softmax ----------------
__global__ __launch_bounds__(128) void k_pool(const float* __restrict__ hout,
                                              const float* __restrict__ energy,
                                              const float* __restrict__ fc_w,
                                              const float* __restrict__ fc_b,
                                              float* __restrict__ outp) {
    __shared__ float red[128];
    __shared__ float wexp[TLEN];
    __shared__ float pooledL[HDIM];
    const int tid = threadIdx.x;
    const int b = blockIdx.x;
    float v[4];
    #pragma unroll
    for (int k = 0; k < 4; ++k) v[k] = energy[b * TLEN + tid + 128 * k];
    float m = fmaxf(fmaxf(v[0], v[1]), fmaxf(v[2], v[3]));
    red[tid] = m; __syncthreads();
    for (int s = 64; s > 0; s >>= 1) {
        if (tid < s) red[tid] = fmaxf(red[tid], red[tid + s]);
        __syncthreads();
    }
    const float M = red[0]; __syncthreads();
    float s4 = 0.f;
    #pragma unroll
    for (int k = 0; k < 4; ++k) {
        float ex = __expf(v[k] - M);
        wexp[tid + 128 * k] = ex;
        s4 += ex;
    }
    red[tid] = s4; __syncthreads();
    for (int s = 64; s > 0; s >>= 1) {
        if (tid < s) red[tid] += red[tid + s];
        __syncthreads();
    }
    const float rinv = 1.0f / red[0];
    if (tid < HDIM) {
        float a0 = 0.f, a1 = 0.f, a2 = 0.f, a3 = 0.f;
        const float* hp = hout + (size_t)b * TLEN * HPAD + tid;
        for (int s = 0; s < TLEN; s += 4) {
            a0 += wexp[s]     * hp[(size_t)(s)     * HPAD];
            a1 += wexp[s + 1] * hp[(size_t)(s + 1) * HPAD];
            a2 += wexp[s + 2] * hp[(size_t)(s + 2) * HPAD];
            a3 += wexp[s + 3] * hp[(size_t)(s + 3) * HPAD];
        }
        pooledL[tid] = ((a0 + a1) + (a2 + a3)) * rinv;
    }
    __syncthreads();
    if (tid == 0) {
        float l[3];
        #pragma unroll
        for (int i = 0; i < 3; ++i) {
            float a = fc_b[i];
            for (int h = 0; h < HDIM; ++h) a += fc_w[i * HDIM + h] * pooledL[h];
            l[i] = a;
        }
        float m3 = fmaxf(l[0], fmaxf(l[1], l[2]));
        float e0 = __expf(l[0] - m3), e1 = __expf(l[1] - m3), e2 = __expf(l[2] - m3);
        float rs = 1.0f / (e0 + e1 + e2);
        outp[b * 3 + 0] = e0 * rs;
        outp[b * 3 + 1] = e1 * rs;
        outp[b * 3 + 2] = e2 * rs;
    }
}

extern "C" void kernel_launch(void* const* d_in, const int* in_sizes, int n_in,
                              void* d_out, int out_size, void* d_ws, size_t ws_size,
                              hipStream_t stream) {
    const float* x       = (const float*)d_in[0];
    const float* embed_w = (const float*)d_in[1];
    const float* w_ih    = (const float*)d_in[2];
    const float* w_hh    = (const float*)d_in[3];
    const float* b_ih    = (const float*)d_in[4];
    const float* b_hh    = (const float*)d_in[5];
    const float* aw1     = (const float*)d_in[6];
    const float* ab1     = (const float*)d_in[7];
    const float* aw2     = (const float*)d_in[8];
    const float* ab2     = (const float*)d_in[9];
    const float* fc_w    = (const float*)d_in[10];
    const float* fc_b    = (const float*)d_in[11];
    float* outp = (float*)d_out;
    float* ws = (float*)d_ws;

    float* wrn  = ws + OFF_WRN;
    float* bias = ws + OFF_BIAS;
    unsigned short* wcT = (unsigned short*)(ws + OFF_WCT);
    unsigned short* xgp = (unsigned short*)(ws + OFF_XG);
    float* ho = ws + OFF_HOUT;
    float* en = ws + OFF_EN;

    k_renorm<<<CDIM, 64, 0, stream>>>(embed_w, wrn);
    k_prep<<<NG, 256, 0, stream>>>(wrn, w_ih, b_ih, b_hh, wcT, bias);
    k_xg_gemm<<<512, 256, 0, stream>>>(x, wcT, bias, xgp);
    k_lstm<<<BATCH, 192, 0, stream>>>(xgp, w_hh, ho);
    k_energy<<<1024, 256, 0, stream>>>(ho, aw1, ab1, aw2, ab2, en);
    k_pool<<<BATCH, 128, 0, stream>>>(ho, en, fc_w, fc_b, outp);
}